// Round 1
// baseline (250.112 us; speedup 1.0000x reference)
//
#include <hip/hip_runtime.h>
#include <math.h>

#define H_    8
#define DH_   64
#define SPD   512
#define NSEQ  2048
#define BATCH 4
#define ROWS  8192
#define KDIM  513
#define KPAD  544
#define INVK  10.0f
#define SQRTK 0.31622776601683794f
#define SCALE_ 0.125f

using bf16x8 = __attribute__((ext_vector_type(8))) short;
using f32x4  = __attribute__((ext_vector_type(4))) float;

static __device__ __forceinline__ short f2bf(float f){
  union { float f; unsigned u; } v; v.f = f;
  unsigned r = v.u + 0x7fffu + ((v.u >> 16) & 1u);
  return (short)(r >> 16);
}
static __device__ __forceinline__ float bf2f(short s){
  union { unsigned u; float f; } v; v.u = ((unsigned)(unsigned short)s) << 16;
  return v.f;
}

// ---------------- conversions ----------------
__global__ __launch_bounds__(256) void convx_kernel(const float* __restrict__ x,
                                                    short* __restrict__ xb){
  int i = blockIdx.x * 256 + threadIdx.x;
  if (i >= ROWS * KPAD) return;
  int r = i / KPAD, c = i - r * KPAD;
  xb[i] = (c < KDIM) ? f2bf(x[(size_t)r * KDIM + c]) : (short)0;
}

// WT[w][n*KPAD + k] = W_w[k][n] (bf16, k zero-padded to KPAD)
__global__ __launch_bounds__(256) void convw_kernel(const float* __restrict__ Wq,
                                                    const float* __restrict__ Wk,
                                                    const float* __restrict__ Wv,
                                                    const float* __restrict__ Wo,
                                                    short* __restrict__ WT){
  int wsel = blockIdx.y;
  const float* W = (wsel == 0) ? Wq : (wsel == 1) ? Wk : (wsel == 2) ? Wv : Wo;
  int i = blockIdx.x * 256 + threadIdx.x;
  if (i >= SPD * KPAD) return;
  int n = i / KPAD, k = i - n * KPAD;
  WT[(size_t)wsel * SPD * KPAD + i] = (k < KDIM) ? f2bf(W[(size_t)k * SPD + n]) : (short)0;
}

// ---------------- GEMM: C[M,512] = A[M,KPAD] @ W^T  (+bias) ----------------
// 128x128 tile, BK=32, 4 waves (2x2), 16x16x32 bf16 MFMA.
template<bool BF16OUT>
__global__ __launch_bounds__(256) void gemm_kernel(
    const short* __restrict__ A, const short* __restrict__ WTbase,
    int sel0, int sel1, int sel2,
    const float* __restrict__ bias0, const float* __restrict__ bias1,
    const float* __restrict__ bias2,
    void* __restrict__ C0, void* __restrict__ C1, void* __restrict__ C2,
    int ldc, int coff)
{
  const int z = blockIdx.z;
  const int sel = (z == 0) ? sel0 : (z == 1) ? sel1 : sel2;
  const short* BT = WTbase + (size_t)sel * SPD * KPAD;
  const float* bias = (z == 0) ? bias0 : (z == 1) ? bias1 : bias2;
  void* C = (z == 0) ? C0 : (z == 1) ? C1 : C2;

  __shared__ short As[128 * 32];
  __shared__ short Bs[128 * 32];

  const int tid  = threadIdx.x;
  const int lane = tid & 63;
  const int wave = tid >> 6;
  const int row0 = blockIdx.x * 128;
  const int col0 = blockIdx.y * 128;
  const int wr = (wave >> 1) * 64;
  const int wc = (wave & 1) * 64;
  const int rA  = lane & 15;
  const int kg2 = (lane >> 4) * 16;  // k-group byte offset within 64B row

  f32x4 acc[4][4] = {};

  for (int kt = 0; kt < KPAD / 32; ++kt){
    __syncthreads();
    #pragma unroll
    for (int p = 0; p < 2; ++p){
      const int idx = p * 256 + tid;
      const int r = idx >> 2;
      const int cb = (idx & 3) * 8;
      const uint4 va = *(const uint4*)(A  + (size_t)(row0 + r) * KPAD + kt * 32 + cb);
      const uint4 vb = *(const uint4*)(BT + (size_t)(col0 + r) * KPAD + kt * 32 + cb);
      const int off = (r * 64 + cb * 2) ^ ((r & 3) << 4);
      *(uint4*)((char*)As + off) = va;
      *(uint4*)((char*)Bs + off) = vb;
    }
    __syncthreads();
    bf16x8 af[4], bfr[4];
    #pragma unroll
    for (int m = 0; m < 4; ++m){
      const int r = wr + m * 16 + rA;
      af[m] = *(const bf16x8*)((const char*)As + ((r * 64 + kg2) ^ ((r & 3) << 4)));
    }
    #pragma unroll
    for (int n = 0; n < 4; ++n){
      const int r = wc + n * 16 + rA;
      bfr[n] = *(const bf16x8*)((const char*)Bs + ((r * 64 + kg2) ^ ((r & 3) << 4)));
    }
    #pragma unroll
    for (int m = 0; m < 4; ++m)
      #pragma unroll
      for (int n = 0; n < 4; ++n)
        acc[m][n] = __builtin_amdgcn_mfma_f32_16x16x32_bf16(af[m], bfr[n], acc[m][n], 0, 0, 0);
  }

  #pragma unroll
  for (int m = 0; m < 4; ++m){
    const int row = row0 + wr + m * 16 + (lane >> 4) * 4;
    #pragma unroll
    for (int n = 0; n < 4; ++n){
      const int col = col0 + wc + n * 16 + rA;
      const float bv = bias[col];
      #pragma unroll
      for (int j = 0; j < 4; ++j){
        const float v = acc[m][n][j] + bv;
        if (BF16OUT) ((short*)C)[(size_t)(row + j) * SPD + col] = f2bf(v);
        else         ((float*)C)[(size_t)(row + j) * ldc + coff + col] = v;
      }
    }
  }
}

// ---------------- post-QKV: t_q, t_k, v_tan (logmap0), transposed V ----------------
__global__ __launch_bounds__(512) void postqkv_kernel(
    const short* __restrict__ qb, const short* __restrict__ kb,
    const short* __restrict__ vb, float* __restrict__ tq, float* __restrict__ tk,
    short* __restrict__ vtT)
{
  const int row = blockIdx.x;
  const int t = threadIdx.x;
  const int lane = t & 63;
  const int w = t >> 6;   // == head index
  __shared__ float red[8];

  float q = bf2f(qb[(size_t)row * SPD + t]);
  float s = q * q;
  #pragma unroll
  for (int m = 32; m; m >>= 1) s += __shfl_xor(s, m, 64);
  if (lane == 0) red[w] = s;
  __syncthreads();
  float tot = 0.f;
  #pragma unroll
  for (int i = 0; i < 8; ++i) tot += red[i];
  if (t == 0) tq[row] = sqrtf(INVK + tot);
  __syncthreads();

  float kk = bf2f(kb[(size_t)row * SPD + t]);
  s = kk * kk;
  #pragma unroll
  for (int m = 32; m; m >>= 1) s += __shfl_xor(s, m, 64);
  if (lane == 0) red[w] = s;
  __syncthreads();
  tot = 0.f;
  #pragma unroll
  for (int i = 0; i < 8; ++i) tot += red[i];
  if (t == 0) tk[row] = sqrtf(INVK + tot);
  __syncthreads();

  float v = bf2f(vb[(size_t)row * SPD + t]);
  s = v * v;
  #pragma unroll
  for (int m = 32; m; m >>= 1) s += __shfl_xor(s, m, 64);  // per-head ssq
  if (lane == 0) red[w] = s;
  __syncthreads();
  tot = 0.f;
  #pragma unroll
  for (int i = 0; i < 8; ++i) tot += red[i];
  const float tv = sqrtf(INVK + tot);
  const float av = fmaxf(SQRTK * tv, 1.0f + 1e-7f);
  const float theta = __logf(av + sqrtf(av * av - 1.0f));   // acosh
  const float fac = theta * (1.0f / SQRTK);
  const float nrm = sqrtf(s);
  const float vt = fac * v / fmaxf(nrm, 1e-9f);
  const int b = row >> 11, n = row & (NSEQ - 1);
  vtT[((size_t)((b * H_ + w) * DH_ + lane)) * NSEQ + n] = f2bf(vt);
}

// ---------------- flash attention + expmap0 spatial part ----------------
__global__ __launch_bounds__(256) void attn_kernel(
    const short* __restrict__ qb, const short* __restrict__ kb,
    const short* __restrict__ vtT, const float* __restrict__ tqg,
    const float* __restrict__ tkg, short* __restrict__ catb)
{
  const int qt = blockIdx.x;
  const int bh = blockIdx.y;
  const int b = bh >> 3, h = bh & 7;
  const int q0 = qt * 64;
  const int tid = threadIdx.x, lane = tid & 63, w = tid >> 6;
  const int rA = lane & 15;
  const int g4 = lane >> 4;
  const int kg2 = g4 * 16;

  __shared__ short Qs[64 * 64];
  __shared__ short Ks[64 * 64];
  __shared__ short Vs[64 * 64];   // [d][m]
  __shared__ short Ps[4][16 * 64];
  __shared__ float tqs[64];
  __shared__ float tks[64];

  {
    const size_t qbase = ((size_t)(b * NSEQ + q0)) * SPD + h * DH_;
    #pragma unroll
    for (int p = 0; p < 2; ++p){
      const int idx = p * 256 + tid;
      const int r = idx >> 3, c8 = (idx & 7) * 8;
      const uint4 vq = *(const uint4*)(qb + qbase + (size_t)r * SPD + c8);
      *(uint4*)((char*)Qs + ((r * 128 + c8 * 2) ^ ((r & 7) << 4))) = vq;
    }
    if (tid < 64) tqs[tid] = tqg[b * NSEQ + q0 + tid];
  }
  __syncthreads();

  bf16x8 qf[2];
  #pragma unroll
  for (int kk = 0; kk < 2; ++kk){
    const int r = w * 16 + rA;
    qf[kk] = *(const bf16x8*)((const char*)Qs + ((r * 128 + kk * 64 + kg2) ^ ((r & 7) << 4)));
  }
  float tqr[4];
  #pragma unroll
  for (int j = 0; j < 4; ++j) tqr[j] = tqs[w * 16 + g4 * 4 + j];

  float m_run[4], l_run[4];
  f32x4 o[4] = {};
  #pragma unroll
  for (int j = 0; j < 4; ++j){ m_run[j] = -1e30f; l_run[j] = 0.f; }

  for (int mc = 0; mc < NSEQ / 64; ++mc){
    const int m0 = mc * 64;
    __syncthreads();
    {
      const size_t kbase = ((size_t)(b * NSEQ + m0)) * SPD + h * DH_;
      const size_t vbase = ((size_t)bh * DH_) * NSEQ + m0;
      #pragma unroll
      for (int p = 0; p < 2; ++p){
        const int idx = p * 256 + tid;
        const int r = idx >> 3, c8 = (idx & 7) * 8;
        const int off = (r * 128 + c8 * 2) ^ ((r & 7) << 4);
        const uint4 vk = *(const uint4*)(kb + kbase + (size_t)r * SPD + c8);
        *(uint4*)((char*)Ks + off) = vk;
        const uint4 vv = *(const uint4*)(vtT + vbase + (size_t)r * NSEQ + c8);
        *(uint4*)((char*)Vs + off) = vv;
      }
      if (tid < 64) tks[tid] = tkg[b * NSEQ + m0 + tid];
    }
    __syncthreads();

    // S = Q K^T
    f32x4 sf[4];
    #pragma unroll
    for (int nf = 0; nf < 4; ++nf){
      f32x4 zz = {};
      #pragma unroll
      for (int kk = 0; kk < 2; ++kk){
        const int r = nf * 16 + rA;
        const bf16x8 kf = *(const bf16x8*)((const char*)Ks +
            ((r * 128 + kk * 64 + kg2) ^ ((r & 7) << 4)));
        zz = __builtin_amdgcn_mfma_f32_16x16x32_bf16(qf[kk], kf, zz, 0, 0, 0);
      }
      sf[nf] = zz;
    }

    float tkc[4];
    #pragma unroll
    for (int nf = 0; nf < 4; ++nf) tkc[nf] = tks[nf * 16 + rA];

    float P[4][4];
    float rmax[4];
    #pragma unroll
    for (int j = 0; j < 4; ++j) rmax[j] = -1e30f;
    #pragma unroll
    for (int nf = 0; nf < 4; ++nf)
      #pragma unroll
      for (int j = 0; j < 4; ++j){
        const float sv = (sf[nf][j] - tqr[j] * tkc[nf]) * SCALE_;
        P[nf][j] = sv;
        rmax[j] = fmaxf(rmax[j], sv);
      }
    #pragma unroll
    for (int od = 1; od < 16; od <<= 1)
      #pragma unroll
      for (int j = 0; j < 4; ++j)
        rmax[j] = fmaxf(rmax[j], __shfl_xor(rmax[j], od, 64));

    float scl[4];
    #pragma unroll
    for (int j = 0; j < 4; ++j){
      const float mn = fmaxf(m_run[j], rmax[j]);
      scl[j] = __expf(m_run[j] - mn);
      m_run[j] = mn;
    }
    float rs[4] = {0.f, 0.f, 0.f, 0.f};
    #pragma unroll
    for (int nf = 0; nf < 4; ++nf)
      #pragma unroll
      for (int j = 0; j < 4; ++j){
        const float pv = __expf(P[nf][j] - m_run[j]);
        P[nf][j] = pv;
        rs[j] += pv;
      }
    #pragma unroll
    for (int od = 1; od < 16; od <<= 1)
      #pragma unroll
      for (int j = 0; j < 4; ++j) rs[j] += __shfl_xor(rs[j], od, 64);
    #pragma unroll
    for (int j = 0; j < 4; ++j) l_run[j] = l_run[j] * scl[j] + rs[j];
    #pragma unroll
    for (int df = 0; df < 4; ++df)
      #pragma unroll
      for (int j = 0; j < 4; ++j) o[df][j] *= scl[j];

    // P -> per-wave LDS (bf16), then PV via MFMA
    #pragma unroll
    for (int nf = 0; nf < 4; ++nf)
      #pragma unroll
      for (int j = 0; j < 4; ++j){
        const int pr = g4 * 4 + j;
        const int off = (pr * 128 + (rA + 16 * nf) * 2) ^ ((pr & 7) << 4);
        *(short*)((char*)(&Ps[w][0]) + off) = f2bf(P[nf][j]);
      }

    #pragma unroll
    for (int kk = 0; kk < 2; ++kk){
      const bf16x8 pa = *(const bf16x8*)((const char*)(&Ps[w][0]) +
          ((rA * 128 + kk * 64 + kg2) ^ ((rA & 7) << 4)));
      #pragma unroll
      for (int df = 0; df < 4; ++df){
        const int r = df * 16 + rA;
        const bf16x8 vf = *(const bf16x8*)((const char*)Vs +
            ((r * 128 + kk * 64 + kg2) ^ ((r & 7) << 4)));
        o[df] = __builtin_amdgcn_mfma_f32_16x16x32_bf16(pa, vf, o[df], 0, 0, 0);
      }
    }
  }

  // epilogue: normalize, expmap0 (time part is discarded downstream -> skipped)
  float ssq[4] = {0.f, 0.f, 0.f, 0.f};
  #pragma unroll
  for (int df = 0; df < 4; ++df)
    #pragma unroll
    for (int j = 0; j < 4; ++j){
      const float vv = o[df][j] / l_run[j];
      o[df][j] = vv;
      ssq[j] += vv * vv;
    }
  #pragma unroll
  for (int od = 1; od < 16; od <<= 1)
    #pragma unroll
    for (int j = 0; j < 4; ++j) ssq[j] += __shfl_xor(ssq[j], od, 64);

  float fac[4];
  #pragma unroll
  for (int j = 0; j < 4; ++j){
    const float nrm = sqrtf(ssq[j]);
    const float sk = SQRTK * nrm;
    const float e = __expf(sk);
    const float sh = 0.5f * (e - 1.0f / e);
    fac[j] = sh / (SQRTK * fmaxf(nrm, 1e-9f));
  }
  #pragma unroll
  for (int df = 0; df < 4; ++df)
    #pragma unroll
    for (int j = 0; j < 4; ++j){
      const int row = b * NSEQ + q0 + w * 16 + g4 * 4 + j;
      const int col = 1 + h * DH_ + df * 16 + rA;
      catb[(size_t)row * KPAD + col] = f2bf(fac[j] * o[df][j]);
    }
}

// ---------------- t' column + zero pad of cat ----------------
__global__ __launch_bounds__(512) void tprime_kernel(short* __restrict__ catb){
  const int row = blockIdx.x;
  const int t = threadIdx.x, lane = t & 63, w = t >> 6;
  __shared__ float red[8];
  float v = bf2f(catb[(size_t)row * KPAD + 1 + t]);
  float s = v * v;
  #pragma unroll
  for (int m = 32; m; m >>= 1) s += __shfl_xor(s, m, 64);
  if (lane == 0) red[w] = s;
  __syncthreads();
  float tot = 0.f;
  #pragma unroll
  for (int i = 0; i < 8; ++i) tot += red[i];
  if (t == 0) catb[(size_t)row * KPAD] = f2bf(sqrtf(fmaxf(INVK + tot, 1e-9f)));
  if (t < KPAD - KDIM) catb[(size_t)row * KPAD + KDIM + t] = 0;
}

// ---------------- final t_o column ----------------
__global__ __launch_bounds__(512) void finalize_kernel(float* __restrict__ out){
  const int row = blockIdx.x;
  const int t = threadIdx.x, lane = t & 63, w = t >> 6;
  __shared__ float red[8];
  float v = out[(size_t)row * KDIM + 1 + t];
  float s = v * v;
  #pragma unroll
  for (int m = 32; m; m >>= 1) s += __shfl_xor(s, m, 64);
  if (lane == 0) red[w] = s;
  __syncthreads();
  float tot = 0.f;
  #pragma unroll
  for (int i = 0; i < 8; ++i) tot += red[i];
  if (t == 0) out[(size_t)row * KDIM] = sqrtf(fmaxf(INVK + tot, 1e-9f));
}

extern "C" void kernel_launch(void* const* d_in, const int* in_sizes, int n_in,
                              void* d_out, int out_size, void* d_ws, size_t ws_size,
                              hipStream_t stream)
{
  (void)in_sizes; (void)n_in; (void)out_size; (void)ws_size;
  const float* x  = (const float*)d_in[0];
  const float* Wq = (const float*)d_in[1];
  const float* bq = (const float*)d_in[2];
  const float* Wk = (const float*)d_in[3];
  const float* bk = (const float*)d_in[4];
  const float* Wv = (const float*)d_in[5];
  const float* bv = (const float*)d_in[6];
  const float* Wo = (const float*)d_in[7];
  const float* bo = (const float*)d_in[8];
  float* out = (float*)d_out;

  char* p = (char*)d_ws;
  short* xb   = (short*)p; p += (size_t)ROWS * KPAD * 2;        // 8.5 MB
  short* WT   = (short*)p; p += (size_t)4 * SPD * KPAD * 2;     // 2.2 MB
  short* qb   = (short*)p; p += (size_t)ROWS * SPD * 2;         // 8 MB
  short* kb   = (short*)p; p += (size_t)ROWS * SPD * 2;
  short* vb   = (short*)p; p += (size_t)ROWS * SPD * 2;
  short* vtT  = (short*)p; p += (size_t)ROWS * SPD * 2;
  float* tq   = (float*)p; p += (size_t)ROWS * 4;
  float* tk   = (float*)p; p += (size_t)ROWS * 4;
  short* catb = (short*)p; p += (size_t)ROWS * KPAD * 2;

  convx_kernel<<<(ROWS * KPAD) / 256, 256, 0, stream>>>(x, xb);
  convw_kernel<<<dim3((SPD * KPAD + 255) / 256, 4), 256, 0, stream>>>(Wq, Wk, Wv, Wo, WT);
  gemm_kernel<true><<<dim3(64, 4, 3), 256, 0, stream>>>(
      xb, WT, 0, 1, 2, bq, bk, bv, qb, kb, vb, SPD, 0);
  postqkv_kernel<<<ROWS, 512, 0, stream>>>(qb, kb, vb, tq, tk, vtT);
  attn_kernel<<<dim3(32, 32), 256, 0, stream>>>(qb, kb, vtT, tq, tk, catb);
  tprime_kernel<<<ROWS, 512, 0, stream>>>(catb);
  gemm_kernel<false><<<dim3(64, 4, 1), 256, 0, stream>>>(
      catb, WT, 3, 3, 3, bo, bo, bo, out, out, out, KDIM, 1);
  finalize_kernel<<<ROWS, 512, 0, stream>>>(out);
}

// Round 3
// 209.193 us; speedup vs baseline: 1.1956x; 1.1956x over previous
//
#include <hip/hip_runtime.h>
#include <math.h>

#define H_    8
#define DH_   64
#define SPD   512
#define NSEQ  2048
#define BATCH 4
#define ROWS  8192
#define KDIM  513
#define KPAD  544
#define INVK  10.0f
#define SQRTK 0.31622776601683794f
#define SCALE_ 0.125f
#define S2C   0.18033688011112043f   // SCALE * log2(e)
#define LOG2E 1.4426950408889634f

using bf16x8 = __attribute__((ext_vector_type(8))) short;
using f32x4  = __attribute__((ext_vector_type(4))) float;
using f32x16 = __attribute__((ext_vector_type(16))) float;

static __device__ __forceinline__ short f2bf(float f){
  union { float f; unsigned u; } v; v.f = f;
  unsigned r = v.u + 0x7fffu + ((v.u >> 16) & 1u);
  return (short)(r >> 16);
}
static __device__ __forceinline__ float bf2f(short s){
  union { unsigned u; float f; } v; v.u = ((unsigned)(unsigned short)s) << 16;
  return v.f;
}
static __device__ __forceinline__ unsigned cvtpk(float lo, float hi){
  unsigned r; asm("v_cvt_pk_bf16_f32 %0, %1, %2" : "=v"(r) : "v"(lo), "v"(hi)); return r;
}
static __device__ __forceinline__ void plswapf(float& a, float& b){
  asm("v_permlane32_swap_b32 %0, %1" : "+v"(a), "+v"(b));
}
static __device__ __forceinline__ void plswapu(unsigned& a, unsigned& b){
  asm("v_permlane32_swap_b32 %0, %1" : "+v"(a), "+v"(b));
}

// ---------------- conversions ----------------
__global__ __launch_bounds__(256) void convx_kernel(const float* __restrict__ x,
                                                    short* __restrict__ xb){
  int i = blockIdx.x * 256 + threadIdx.x;
  if (i >= ROWS * KPAD) return;
  int r = i / KPAD, c = i - r * KPAD;
  xb[i] = (c < KDIM) ? f2bf(x[(size_t)r * KDIM + c]) : (short)0;
}

__global__ __launch_bounds__(256) void convw_kernel(const float* __restrict__ Wq,
                                                    const float* __restrict__ Wk,
                                                    const float* __restrict__ Wv,
                                                    const float* __restrict__ Wo,
                                                    short* __restrict__ WT){
  int wsel = blockIdx.y;
  const float* W = (wsel == 0) ? Wq : (wsel == 1) ? Wk : (wsel == 2) ? Wv : Wo;
  int i = blockIdx.x * 256 + threadIdx.x;
  if (i >= SPD * KPAD) return;
  int n = i / KPAD, k = i - n * KPAD;
  WT[(size_t)wsel * SPD * KPAD + i] = (k < KDIM) ? f2bf(W[(size_t)k * SPD + n]) : (short)0;
}

// ---------------- GEMM: C[M,512] = A[M,KPAD] @ W^T  (+bias) ----------------
template<bool BF16OUT>
__global__ __launch_bounds__(256) void gemm_kernel(
    const short* __restrict__ A, const short* __restrict__ WTbase,
    int sel0, int sel1, int sel2,
    const float* __restrict__ bias0, const float* __restrict__ bias1,
    const float* __restrict__ bias2,
    void* __restrict__ C0, void* __restrict__ C1, void* __restrict__ C2,
    int ldc, int coff)
{
  const int z = blockIdx.z;
  const int sel = (z == 0) ? sel0 : (z == 1) ? sel1 : sel2;
  const short* BT = WTbase + (size_t)sel * SPD * KPAD;
  const float* bias = (z == 0) ? bias0 : (z == 1) ? bias1 : bias2;
  void* C = (z == 0) ? C0 : (z == 1) ? C1 : C2;

  __shared__ short As[128 * 32];
  __shared__ short Bs[128 * 32];

  const int tid  = threadIdx.x;
  const int lane = tid & 63;
  const int wave = tid >> 6;
  const int row0 = blockIdx.x * 128;
  const int col0 = blockIdx.y * 128;
  const int wr = (wave >> 1) * 64;
  const int wc = (wave & 1) * 64;
  const int rA  = lane & 15;
  const int kg2 = (lane >> 4) * 16;

  f32x4 acc[4][4] = {};

  for (int kt = 0; kt < KPAD / 32; ++kt){
    __syncthreads();
    #pragma unroll
    for (int p = 0; p < 2; ++p){
      const int idx = p * 256 + tid;
      const int r = idx >> 2;
      const int cb = (idx & 3) * 8;
      const uint4 va = *(const uint4*)(A  + (size_t)(row0 + r) * KPAD + kt * 32 + cb);
      const uint4 vb = *(const uint4*)(BT + (size_t)(col0 + r) * KPAD + kt * 32 + cb);
      const int off = (r * 64 + cb * 2) ^ ((r & 3) << 4);
      *(uint4*)((char*)As + off) = va;
      *(uint4*)((char*)Bs + off) = vb;
    }
    __syncthreads();
    bf16x8 af[4], bfr[4];
    #pragma unroll
    for (int m = 0; m < 4; ++m){
      const int r = wr + m * 16 + rA;
      af[m] = *(const bf16x8*)((const char*)As + ((r * 64 + kg2) ^ ((r & 3) << 4)));
    }
    #pragma unroll
    for (int n = 0; n < 4; ++n){
      const int r = wc + n * 16 + rA;
      bfr[n] = *(const bf16x8*)((const char*)Bs + ((r * 64 + kg2) ^ ((r & 3) << 4)));
    }
    #pragma unroll
    for (int m = 0; m < 4; ++m)
      #pragma unroll
      for (int n = 0; n < 4; ++n)
        acc[m][n] = __builtin_amdgcn_mfma_f32_16x16x32_bf16(af[m], bfr[n], acc[m][n], 0, 0, 0);
  }

  #pragma unroll
  for (int m = 0; m < 4; ++m){
    const int row = row0 + wr + m * 16 + (lane >> 4) * 4;
    #pragma unroll
    for (int n = 0; n < 4; ++n){
      const int col = col0 + wc + n * 16 + rA;
      const float bv = bias[col];
      #pragma unroll
      for (int j = 0; j < 4; ++j){
        const float v = acc[m][n][j] + bv;
        if (BF16OUT) ((short*)C)[(size_t)(row + j) * SPD + col] = f2bf(v);
        else         ((float*)C)[(size_t)(row + j) * ldc + coff + col] = v;
      }
    }
  }
}

// ---------------- post-QKV: t_q, t_k, v_tan (logmap0), transposed V ----------------
__global__ __launch_bounds__(512) void postqkv_kernel(
    const short* __restrict__ qb, const short* __restrict__ kb,
    const short* __restrict__ vb, float* __restrict__ tq, float* __restrict__ tk,
    short* __restrict__ vtT)
{
  const int row = blockIdx.x;
  const int t = threadIdx.x;
  const int lane = t & 63;
  const int w = t >> 6;
  __shared__ float red[8];

  float q = bf2f(qb[(size_t)row * SPD + t]);
  float s = q * q;
  #pragma unroll
  for (int m = 32; m; m >>= 1) s += __shfl_xor(s, m, 64);
  if (lane == 0) red[w] = s;
  __syncthreads();
  float tot = 0.f;
  #pragma unroll
  for (int i = 0; i < 8; ++i) tot += red[i];
  if (t == 0) tq[row] = sqrtf(INVK + tot);
  __syncthreads();

  float kk = bf2f(kb[(size_t)row * SPD + t]);
  s = kk * kk;
  #pragma unroll
  for (int m = 32; m; m >>= 1) s += __shfl_xor(s, m, 64);
  if (lane == 0) red[w] = s;
  __syncthreads();
  tot = 0.f;
  #pragma unroll
  for (int i = 0; i < 8; ++i) tot += red[i];
  if (t == 0) tk[row] = sqrtf(INVK + tot);
  __syncthreads();

  float v = bf2f(vb[(size_t)row * SPD + t]);
  s = v * v;
  #pragma unroll
  for (int m = 32; m; m >>= 1) s += __shfl_xor(s, m, 64);
  if (lane == 0) red[w] = s;
  __syncthreads();
  tot = 0.f;
  #pragma unroll
  for (int i = 0; i < 8; ++i) tot += red[i];
  const float tv = sqrtf(INVK + tot);
  const float av = fmaxf(SQRTK * tv, 1.0f + 1e-7f);
  const float theta = __logf(av + sqrtf(av * av - 1.0f));
  const float fac = theta * (1.0f / SQRTK);
  const float nrm = sqrtf(s);
  const float vt = fac * v / fmaxf(nrm, 1e-9f);
  const int b = row >> 11, n = row & (NSEQ - 1);
  vtT[((size_t)((b * H_ + w) * DH_ + lane)) * NSEQ + n] = f2bf(vt);
}

// ---------------- flash attention (swapped QK^T, in-register softmax) ----------------
__global__ __launch_bounds__(256) void attn_kernel(
    const short* __restrict__ qb, const short* __restrict__ kb,
    const short* __restrict__ vtT, const float* __restrict__ tqg,
    const float* __restrict__ tkg, short* __restrict__ catb)
{
  int bid = blockIdx.x;
  bid = (bid & 7) * 64 + (bid >> 3);          // XCD-chunked swizzle (512 = 8*64)
  const int qt = bid & 15;
  const int bh = bid >> 4;
  const int b = bh >> 3, h = bh & 7;
  const int q0 = qt * 128;
  const int tid = threadIdx.x;
  const int lane = tid & 63;
  const int w = tid >> 6;
  const int l31 = lane & 31;
  const int hi = lane >> 5;
  const int rsw = (l31 & 7) << 4;

  __shared__ short Ks[2][64 * 64];
  __shared__ short Vs[2][64 * 64];   // V^T tile: rows d, cols kv
  __shared__ float lred[4][32];

  // Q fragments (B-operand): q = q0 + w*32 + l31, d = s*16 + hi*8 + j
  const int qrow = q0 + w * 32 + l31;
  bf16x8 qf[4];
  {
    const short* qptr = qb + (size_t)(b * NSEQ + qrow) * SPD + h * DH_ + hi * 8;
    #pragma unroll
    for (int s = 0; s < 4; ++s) qf[s] = *(const bf16x8*)(qptr + s * 16);
  }
  const float negtq = -tqg[b * NSEQ + qrow] * S2C;

  // staging: thread owns rows rB, rB+32; LINEAR global col c0, SWIZZLED LDS col cc
  const int rB = tid >> 3;
  const int c0 = (tid & 7) * 16;                 // byte col within 128B row
  const int cc = c0 ^ ((rB & 7) << 4);           // swizzled LDS byte col
  const short* kbase = kb + (size_t)(b * NSEQ) * SPD + h * DH_;
  const short* vbase = vtT + (size_t)(bh * DH_) * NSEQ;
  uint4 kreg[2], vreg[2];

  auto LOADR = [&](int m0){
    kreg[0] = *(const uint4*)(kbase + (size_t)(m0 + rB) * SPD + (c0 >> 1));
    kreg[1] = *(const uint4*)(kbase + (size_t)(m0 + 32 + rB) * SPD + (c0 >> 1));
    vreg[0] = *(const uint4*)(vbase + (size_t)rB * NSEQ + m0 + (c0 >> 1));
    vreg[1] = *(const uint4*)(vbase + (size_t)(32 + rB) * NSEQ + m0 + (c0 >> 1));
  };
  auto WRITE = [&](int buf){
    *(uint4*)((char*)Ks[buf] + rB * 128 + cc) = kreg[0];
    *(uint4*)((char*)Ks[buf] + (32 + rB) * 128 + cc) = kreg[1];
    *(uint4*)((char*)Vs[buf] + rB * 128 + cc) = vreg[0];
    *(uint4*)((char*)Vs[buf] + (32 + rB) * 128 + cc) = vreg[1];
  };

  float m_run = -1e30f, l_run = 0.f;
  f32x16 o[2] = {};

  LOADR(0);
  WRITE(0);
  __syncthreads();
  int cur = 0;

  for (int mc = 0; mc < NSEQ / 64; ++mc){
    const int m0 = mc * 64;
    if (mc + 1 < NSEQ / 64) LOADR(m0 + 64);

    const char* Kc = (const char*)Ks[cur];
    const char* Vc = (const char*)Vs[cur];

    // tk (broadcast global loads, L2-resident)
    const float* tkp = tkg + b * NSEQ + m0 + 4 * hi;
    f32x4 tk4[2][4];
    #pragma unroll
    for (int f = 0; f < 2; ++f)
      #pragma unroll
      for (int g = 0; g < 4; ++g)
        tk4[f][g] = *(const f32x4*)(tkp + f * 32 + 8 * g);

    // S^T = K · Q^T  (rows kv, cols q)
    f32x16 sacc[2] = {};
    __builtin_amdgcn_s_setprio(1);
    #pragma unroll
    for (int f = 0; f < 2; ++f){
      const int rowb = (f * 32 + l31) * 128;
      #pragma unroll
      for (int s = 0; s < 4; ++s){
        const bf16x8 kf = *(const bf16x8*)(Kc + rowb + ((s * 32 + hi * 16) ^ rsw));
        sacc[f] = __builtin_amdgcn_mfma_f32_32x32x16_bf16(kf, qf[s], sacc[f], 0, 0, 0);
      }
    }
    __builtin_amdgcn_s_setprio(0);

    // scores in log2 domain: sv = sacc*S2C - tq*tk*S2C
    float sv[2][16];
    #pragma unroll
    for (int f = 0; f < 2; ++f)
      #pragma unroll
      for (int e = 0; e < 16; ++e)
        sv[f][e] = fmaf(sacc[f][e], S2C, negtq * tk4[f][e >> 2][e & 3]);

    // column max (in-lane fmax chain + cross-half permlane)
    float pm = sv[0][0];
    #pragma unroll
    for (int e = 1; e < 16; ++e) pm = fmaxf(pm, sv[0][e]);
    #pragma unroll
    for (int e = 0; e < 16; ++e) pm = fmaxf(pm, sv[1][e]);
    { float ca = pm, cb = pm; plswapf(ca, cb); pm = fmaxf(pm, fmaxf(ca, cb)); }

    // defer-max rescale (rare)
    if (!__all(pm <= m_run + 8.0f)){
      const float mn = fmaxf(m_run, pm);
      const float scl = exp2f(m_run - mn);
      m_run = mn;
      l_run *= scl;
      if (lane < 32) lred[w][l31] = scl;
      asm volatile("s_waitcnt lgkmcnt(0)" ::: "memory");
      f32x4 s4[4];
      #pragma unroll
      for (int g = 0; g < 4; ++g) s4[g] = *(const f32x4*)&lred[w][8 * g + 4 * hi];
      #pragma unroll
      for (int e = 0; e < 16; ++e){
        o[0][e] *= s4[e >> 2][e & 3];
        o[1][e] *= s4[e >> 2][e & 3];
      }
    }

    // P = exp2(sv - m), column sum
    float rs = 0.f;
    #pragma unroll
    for (int f = 0; f < 2; ++f)
      #pragma unroll
      for (int e = 0; e < 16; ++e){
        const float p = exp2f(sv[f][e] - m_run);
        sv[f][e] = p;
        rs += p;
      }
    { float ca = rs, cb = rs; plswapf(ca, cb); rs += hi ? ca : cb; }
    l_run += rs;

    // P -> bf16 A-operand fragments via cvt_pk + permlane32_swap (T12)
    bf16x8 pa[4];
    #pragma unroll
    for (int f = 0; f < 2; ++f)
      #pragma unroll
      for (int g16 = 0; g16 < 2; ++g16){
        const int bse = g16 * 8;
        unsigned A0 = cvtpk(sv[f][bse + 0], sv[f][bse + 1]);
        unsigned A1 = cvtpk(sv[f][bse + 2], sv[f][bse + 3]);
        unsigned B0 = cvtpk(sv[f][bse + 4], sv[f][bse + 5]);
        unsigned B1 = cvtpk(sv[f][bse + 6], sv[f][bse + 7]);
        plswapu(A0, B0);   // -> words 0,2 pattern
        plswapu(A1, B1);   // -> words 1,3 pattern
        union { unsigned u[4]; bf16x8 v; } pu;
        pu.u[0] = A0; pu.u[1] = A1; pu.u[2] = B0; pu.u[3] = B1;
        pa[f * 2 + g16] = pu.v;
      }

    // O += P · V
    __builtin_amdgcn_s_setprio(1);
    #pragma unroll
    for (int db = 0; db < 2; ++db){
      const int rowb = (db * 32 + l31) * 128;
      #pragma unroll
      for (int ks = 0; ks < 4; ++ks){
        const bf16x8 vf = *(const bf16x8*)(Vc + rowb + ((ks * 32 + hi * 16) ^ rsw));
        o[db] = __builtin_amdgcn_mfma_f32_32x32x16_bf16(pa[ks], vf, o[db], 0, 0, 0);
      }
    }
    __builtin_amdgcn_s_setprio(0);

    if (mc + 1 < NSEQ / 64) WRITE(cur ^ 1);
    __syncthreads();
    cur ^= 1;
  }

  // epilogue: l broadcast column->row space, normalize, expmap0 spatial part
  if (lane < 32) lred[w][l31] = l_run;
  asm volatile("s_waitcnt lgkmcnt(0)" ::: "memory");
  f32x4 lv[4];
  #pragma unroll
  for (int g = 0; g < 4; ++g) lv[g] = *(const f32x4*)&lred[w][8 * g + 4 * hi];

  const size_t obase = (size_t)(b * NSEQ + q0 + w * 32) * KPAD + 1 + h * DH_ + l31;
  #pragma unroll
  for (int e = 0; e < 16; ++e){
    const float linv = __builtin_amdgcn_rcpf(lv[e >> 2][e & 3]);
    const float ov0 = o[0][e] * linv;
    const float ov1 = o[1][e] * linv;
    float ss = ov0 * ov0 + ov1 * ov1;
    #pragma unroll
    for (int off = 16; off; off >>= 1) ss += __shfl_xor(ss, off, 64);
    const float nrm = sqrtf(ss);
    const float e2 = exp2f(SQRTK * nrm * LOG2E);
    const float einv = __builtin_amdgcn_rcpf(e2);
    const float fac = (e2 - einv) * 0.5f * __builtin_amdgcn_rcpf(SQRTK * fmaxf(nrm, 1e-9f));
    const int crow = (e & 3) + 8 * (e >> 2) + 4 * hi;
    catb[obase + (size_t)crow * KPAD]      = f2bf(fac * ov0);
    catb[obase + (size_t)crow * KPAD + 32] = f2bf(fac * ov1);
  }
}

// ---------------- t' column + zero pad of cat ----------------
__global__ __launch_bounds__(512) void tprime_kernel(short* __restrict__ catb){
  const int row = blockIdx.x;
  const int t = threadIdx.x, lane = t & 63, w = t >> 6;
  __shared__ float red[8];
  float v = bf2f(catb[(size_t)row * KPAD + 1 + t]);
  float s = v * v;
  #pragma unroll
  for (int m = 32; m; m >>= 1) s += __shfl_xor(s, m, 64);
  if (lane == 0) red[w] = s;
  __syncthreads();
  float tot = 0.f;
  #pragma unroll
  for (int i = 0; i < 8; ++i) tot += red[i];
  if (t == 0) catb[(size_t)row * KPAD] = f2bf(sqrtf(fmaxf(INVK + tot, 1e-9f)));
  if (t < KPAD - KDIM) catb[(size_t)row * KPAD + KDIM + t] = 0;
}

// ---------------- final t_o column ----------------
__global__ __launch_bounds__(512) void finalize_kernel(float* __restrict__ out){
  const int row = blockIdx.x;
  const int t = threadIdx.x, lane = t & 63, w = t >> 6;
  __shared__ float red[8];
  float v = out[(size_t)row * KDIM + 1 + t];
  float s = v * v;
  #pragma unroll
  for (int m = 32; m; m >>= 1) s += __shfl_xor(s, m, 64);
  if (lane == 0) red[w] = s;
  __syncthreads();
  float tot = 0.f;
  #pragma unroll
  for (int i = 0; i < 8; ++i) tot += red[i];
  if (t == 0) out[(size_t)row * KDIM] = sqrtf(fmaxf(INVK + tot, 1e-9f));
}

extern "C" void kernel_launch(void* const* d_in, const int* in_sizes, int n_in,
                              void* d_out, int out_size, void* d_ws, size_t ws_size,
                              hipStream_t stream)
{
  (void)in_sizes; (void)n_in; (void)out_size; (void)ws_size;
  const float* x  = (const float*)d_in[0];
  const float* Wq = (const float*)d_in[1];
  const float* bq = (const float*)d_in[2];
  const float* Wk = (const float*)d_in[3];
  const float* bk = (const float*)d_in[4];
  const float* Wv = (const float*)d_in[5];
  const float* bv = (const float*)d_in[6];
  const float* Wo = (const float*)d_in[7];
  const float* bo = (const float*)d_in[8];
  float* out = (float*)d_out;

  char* p = (char*)d_ws;
  short* xb   = (short*)p; p += (size_t)ROWS * KPAD * 2;
  short* WT   = (short*)p; p += (size_t)4 * SPD * KPAD * 2;
  short* qb   = (short*)p; p += (size_t)ROWS * SPD * 2;
  short* kb   = (short*)p; p += (size_t)ROWS * SPD * 2;
  short* vb   = (short*)p; p += (size_t)ROWS * SPD * 2;
  short* vtT  = (short*)p; p += (size_t)ROWS * SPD * 2;
  float* tq   = (float*)p; p += (size_t)ROWS * 4;
  float* tk   = (float*)p; p += (size_t)ROWS * 4;
  short* catb = (short*)p; p += (size_t)ROWS * KPAD * 2;

  convx_kernel<<<(ROWS * KPAD) / 256, 256, 0, stream>>>(x, xb);
  convw_kernel<<<dim3((SPD * KPAD + 255) / 256, 4), 256, 0, stream>>>(Wq, Wk, Wv, Wo, WT);
  gemm_kernel<true><<<dim3(64, 4, 3), 256, 0, stream>>>(
      xb, WT, 0, 1, 2, bq, bk, bv, qb, kb, vb, SPD, 0);
  postqkv_kernel<<<ROWS, 512, 0, stream>>>(qb, kb, vb, tq, tk, vtT);
  attn_kernel<<<512, 256, 0, stream>>>(qb, kb, vtT, tq, tk, catb);
  tprime_kernel<<<ROWS, 512, 0, stream>>>(catb);
  gemm_kernel<false><<<dim3(64, 4, 1), 256, 0, stream>>>(
      catb, WT, 3, 3, 3, bo, bo, bo, out, out, out, KDIM, 1);
  finalize_kernel<<<ROWS, 512, 0, stream>>>(out);
}